// Round 9
// baseline (16084.937 us; speedup 1.0000x reference)
//
#include <hip/hip_runtime.h>
#include <cmath>

#define BATCH 128
#define TLEN  256
#define HDIM  1024
#define CDIM  10
#define NT    1024
#define NWG   256

typedef unsigned long long u64;
typedef unsigned int u32;

// h state, double buffered, k-major, u64 = 2 packed floats: g_hx[buf][j][b/2].
// ALL h accesses are relaxed agent-scope atomics -> MALL-coherent, no fences;
// x/W/bias stay warm in L1/L2 across all 256 steps.
__device__ u64 g_hx[2][HDIM][BATCH / 2];

__device__ __forceinline__ float4 ld4(const float* p) { return *(const float4*)p; }

__device__ __forceinline__ u64 aload(const u64* p) {
    return __hip_atomic_load(p, __ATOMIC_RELAXED, __HIP_MEMORY_SCOPE_AGENT);
}
__device__ __forceinline__ void astore(u64* p, u64 v) {
    __hip_atomic_store(p, v, __ATOMIC_RELAXED, __HIP_MEMORY_SCOPE_AGENT);
}
__device__ __forceinline__ void astore32(u32* p, u32 v) {
    __hip_atomic_store(p, v, __ATOMIC_RELAXED, __HIP_MEMORY_SCOPE_AGENT);
}

// LDS-only barrier (R13): protects LDS handoffs without draining vmcnt.
__device__ __forceinline__ void barrier_lds() {
    asm volatile("s_waitcnt lgkmcnt(0)\n\ts_barrier" ::: "memory");
}

// Group barrier (R11/R12-proven): parallel arrivals on 128 distinct flags,
// per-wave self-release poll, monotonic targets, bounded spin.
// Keeps its explicit vmcnt(0): it is the h-publish release fence.
__device__ __forceinline__ void gbar2(u32* flags, int grp, int idx, u32 target) {
    asm volatile("s_waitcnt vmcnt(0)" ::: "memory");
    __syncthreads();
    if (threadIdx.x == 0)
        astore32(flags + grp * 128 + idx, target);
    const u64* base = (const u64*)(flags + grp * 128) + (threadIdx.x & 63);
    int guard = 0;
    for (;;) {
        const u64 v = aload(base);
        const bool ok = ((u32)v >= target) && ((u32)(v >> 32) >= target);
        if (__all(ok) || ++guard > (1 << 20)) break;
        __builtin_amdgcn_s_sleep(1);
    }
}

#define FMA4(d, s, v) do { (d).x = fmaf((s), (v).x, (d).x); (d).y = fmaf((s), (v).y, (d).y); \
                           (d).z = fmaf((s), (v).z, (d).z); (d).w = fmaf((s), (v).w, (d).w); } while (0)
#define ADD4(d, s)     do { (d).x += (s).x; (d).y += (s).y; (d).z += (s).z; (d).w += (s).w; } while (0)

// R19: barrier-free main loop. h operands are read DIRECTLY from g_hx (MALL)
// in the compute pattern -- no LDS h-staging, no chunk barriers. h loads are
// vmcnt-tracked (separate counter from the lgkm W-reads), so the compiler's
// counted vmcnt waits pipeline chunk c+1's loads under chunk c's FMAs; at
// 4 waves/SIMD the per-chunk wall time (~2k cyc) covers MALL latency (~700).
// Cost: 4x MALL read traffic (jq waves no longer share h) -- the bet is
// MALL BW. W stays in LDS (R15 lesson: W MUST stay in LDS). FMA sequence and
// operand values bit-identical to the proven kernel -> absmax 0.0.
// Barriers per step: 2 (sS exchange) + 1 (gbar2) vs 35 before.
__global__ void __launch_bounds__(NT, 1)
lstm_fused(const float* __restrict__ x,
           const float* __restrict__ Wgx, const float* __restrict__ Wgh, const float* __restrict__ bg,
           const float* __restrict__ Wix, const float* __restrict__ Wih, const float* __restrict__ bi,
           const float* __restrict__ Wfx, const float* __restrict__ Wfh, const float* __restrict__ bf,
           const float* __restrict__ Wox, const float* __restrict__ Woh, const float* __restrict__ bo,
           const float* __restrict__ Wph, const float* __restrict__ bp,
           u32* __restrict__ flags, float* __restrict__ out)
{
    __shared__ float sW[8][HDIM][4];              // [j_local][k][gate], 128 KB
    __shared__ __align__(16) float4 sS[1024];     // cross-kh exchange, 16 KB (dedicated)

    const int tid  = threadIdx.x;
    const int wave = tid >> 6;          // 0..15
    const int jq   = wave >> 2;         // j-pair index (0..3)
    const int kh   = wave & 3;          // k-quarter within chunk
    const int lane = tid & 63;
    const int ks   = lane & 7;
    const int bo8  = lane >> 3;
    const int rgB  = blockIdx.x >> 1;   // j in [8*rgB, 8*rgB+8)  == index in group
    const int bgB  = blockIdx.x & 1;    // b in [64*bgB, 64*bgB+64) == group id

    // ---- stage W once, gate-interleaved (1024 threads: 4 rows per pass) ----
    {
        auto stageW = [&](const float* Wsrc, int g) {
            #pragma unroll
            for (int it = 0; it < 2; ++it) {
                const int row = it * 4 + (tid >> 8);     // 0..7
                const int c4  = tid & 255;               // float4 column
                const float4 v = ld4(Wsrc + (size_t)(rgB * 8 + row) * HDIM + c4 * 4);
                sW[row][c4 * 4 + 0][g] = v.x;
                sW[row][c4 * 4 + 1][g] = v.y;
                sW[row][c4 * 4 + 2][g] = v.z;
                sW[row][c4 * 4 + 3][g] = v.w;
            }
        };
        stageW(Wgh, 0); stageW(Wih, 1); stageW(Wfh, 2); stageW(Woh, 3);
    }

    // epilogue cells: j = rgB*8 + jq*2 + (ks>>2); b = bgB*64 + bo8*8 + (ks&3)*2 + cell.
    const int jc = rgB * 8 + jq * 2 + (ks >> 2);
    const float4 wx4 = make_float4(Wgx[jc], Wix[jc], Wfx[jc], Wox[jc]);
    const float4 b4  = make_float4(bg[jc], bi[jc], bf[jc], bo[jc]);
    const int bloc = bgB * 64 + bo8 * 8 + (ks & 3) * 2;   // cell-0 batch index
    float cst = 0.f;                                       // my cell's c-state

    // zero h0 -- OWN b-half only: 8 j-rows x 32 u64
    if (tid < 256)
        astore(&g_hx[0][rgB * 8 + (tid >> 5)][bgB * 32 + (tid & 31)], 0ull);

    gbar2(flags, bgB, rgB, 1u);         // also publishes sW (syncthreads inside)

    const int kc_ = kh * 8 + ks;                // this lane's k within any chunk
    const int bu0 = bgB * 32 + bo8 * 4;         // lane's b-octet, u64 units

    for (int t = 0; t < TLEN; ++t) {
        const u64* hc = &g_hx[t & 1][0][0];
        u32*       hn32 = (u32*)&g_hx[(t + 1) & 1][0][0];

        // x for my epilogue cell (kh0 -> b, kh2 -> b+1), L1-warm
        float xv = 0.f;
        if ((kh & 1) == 0)
            xv = x[(size_t)(bloc + (kh >> 1)) * TLEN + t];

        // lane's operand row for chunk 0: h[kc_][bu0..bu0+3] (4 u64 = 8 floats)
        const u64* p = hc + (size_t)kc_ * 64 + bu0;
        u64 c0 = aload(p), c1 = aload(p + 1), c2 = aload(p + 2), c3 = aload(p + 3);

        float4 acc[2][8];   // [j_local][b]; components = 4 gates. STATIC indices only.
        #pragma unroll
        for (int jl = 0; jl < 2; ++jl)
            #pragma unroll
            for (int cb = 0; cb < 8; ++cb)
                acc[jl][cb] = make_float4(0.f, 0.f, 0.f, 0.f);

        #pragma unroll 1
        for (int cc = 0; cc < 32; ++cc) {
            u64 n0, n1, n2, n3;
            if (cc + 1 < 32) {          // issue chunk cc+1 loads (fly under FMAs)
                const u64* q = p + 2048;
                n0 = aload(q); n1 = aload(q + 1); n2 = aload(q + 2); n3 = aload(q + 3);
            }
            float4 hA, hB;              // chunk cc operands (bit-identical to staged path)
            {
                float2 f0, f1, f2, f3;
                __builtin_memcpy(&f0, &c0, 8); __builtin_memcpy(&f1, &c1, 8);
                __builtin_memcpy(&f2, &c2, 8); __builtin_memcpy(&f3, &c3, 8);
                hA = make_float4(f0.x, f0.y, f1.x, f1.y);
                hB = make_float4(f2.x, f2.y, f3.x, f3.y);
            }
            const float4 w0 = ld4(&sW[jq * 2 + 0][cc * 32 + kc_][0]);
            const float4 w1 = ld4(&sW[jq * 2 + 1][cc * 32 + kc_][0]);
            FMA4(acc[0][0], hA.x, w0); FMA4(acc[0][1], hA.y, w0);
            FMA4(acc[0][2], hA.z, w0); FMA4(acc[0][3], hA.w, w0);
            FMA4(acc[0][4], hB.x, w0); FMA4(acc[0][5], hB.y, w0);
            FMA4(acc[0][6], hB.z, w0); FMA4(acc[0][7], hB.w, w0);
            FMA4(acc[1][0], hA.x, w1); FMA4(acc[1][1], hA.y, w1);
            FMA4(acc[1][2], hA.z, w1); FMA4(acc[1][3], hA.w, w1);
            FMA4(acc[1][4], hB.x, w1); FMA4(acc[1][5], hB.y, w1);
            FMA4(acc[1][6], hB.z, w1); FMA4(acc[1][7], hB.w, w1);
            c0 = n0; c1 = n1; c2 = n2; c3 = n3;
            p += 2048;                  // 32 rows x 64 u64
        }

        // ---- intra-wave recursive-halving reduction over ks (56 shfl) ----
        float4 r1[8];
        #pragma unroll
        for (int i = 0; i < 8; ++i) {
            const float4 fs = (ks & 4) ? acc[0][i] : acc[1][i];
            float4 fr;
            fr.x = __shfl_xor(fs.x, 4); fr.y = __shfl_xor(fs.y, 4);
            fr.z = __shfl_xor(fs.z, 4); fr.w = __shfl_xor(fs.w, 4);
            const float4 fk = (ks & 4) ? acc[1][i] : acc[0][i];
            r1[i] = make_float4(fk.x + fr.x, fk.y + fr.y, fk.z + fr.z, fk.w + fr.w);
        }
        float4 r2[4];
        #pragma unroll
        for (int i = 0; i < 4; ++i) {
            const float4 fs = (ks & 2) ? r1[i] : r1[i + 4];
            float4 fr;
            fr.x = __shfl_xor(fs.x, 2); fr.y = __shfl_xor(fs.y, 2);
            fr.z = __shfl_xor(fs.z, 2); fr.w = __shfl_xor(fs.w, 2);
            const float4 fk = (ks & 2) ? r1[i + 4] : r1[i];
            r2[i] = make_float4(fk.x + fr.x, fk.y + fr.y, fk.z + fr.z, fk.w + fr.w);
        }
        float4 q0, q1;
        {
            const float4 fs0 = (ks & 1) ? r2[0] : r2[2];
            const float4 fs1 = (ks & 1) ? r2[1] : r2[3];
            float4 fr0, fr1;
            fr0.x = __shfl_xor(fs0.x, 1); fr0.y = __shfl_xor(fs0.y, 1);
            fr0.z = __shfl_xor(fs0.z, 1); fr0.w = __shfl_xor(fs0.w, 1);
            fr1.x = __shfl_xor(fs1.x, 1); fr1.y = __shfl_xor(fs1.y, 1);
            fr1.z = __shfl_xor(fs1.z, 1); fr1.w = __shfl_xor(fs1.w, 1);
            const float4 fk0 = (ks & 1) ? r2[2] : r2[0];
            const float4 fk1 = (ks & 1) ? r2[3] : r2[1];
            q0 = make_float4(fk0.x + fr0.x, fk0.y + fr0.y, fk0.z + fr0.z, fk0.w + fr0.w);
            q1 = make_float4(fk1.x + fr1.x, fk1.y + fr1.y, fk1.z + fr1.z, fk1.w + fr1.w);
        }
        // q0,q1 = partial (this kh) preacts for cells (jc, bloc) and (jc, bloc+1)

        // ---- cross-kh reduction via dedicated sS (no aliasing hazards) ----
        if (kh & 1) {                   // kh1 -> slot(jq,0), kh3 -> slot(jq,1)
            const int sl = ((jq * 2 + (kh >> 1)) * 64 + lane) * 2;
            sS[sl]     = q0;
            sS[sl + 1] = q1;
        }
        barrier_lds();
        if ((kh & 1) == 0) {            // kh0 adds kh1; kh2 adds kh3
            const int sl = ((jq * 2 + (kh >> 1)) * 64 + lane) * 2;
            ADD4(q0, sS[sl]);
            ADD4(q1, sS[sl + 1]);
        }
        // stage 2: kh0 surrenders q1, kh2 surrenders q0 (each keeps its cell)
        if (kh == 0) sS[((jq * 2 + 0) * 64 + lane) * 2 + 1] = q1;
        if (kh == 2) sS[((jq * 2 + 1) * 64 + lane) * 2 + 0] = q0;
        barrier_lds();

        if ((kh & 1) == 0) {
            float4 qq;
            if (kh == 0) {
                ADD4(q0, sS[((jq * 2 + 1) * 64 + lane) * 2 + 0]);
                qq = q0;
            } else {
                ADD4(q1, sS[((jq * 2 + 0) * 64 + lane) * 2 + 1]);
                qq = q1;
            }
            FMA4(qq, xv, wx4);
            qq.x += b4.x; qq.y += b4.y; qq.z += b4.z; qq.w += b4.w;
            const float g_ = tanhf(qq.x);
            const float i_ = 1.f / (1.f + expf(-qq.y));
            const float f_ = 1.f / (1.f + expf(-qq.z));
            const float o_ = 1.f / (1.f + expf(-qq.w));
            cst = g_ * i_ + cst * f_;
            const float hv = tanhf(cst) * o_;
            u32 bits; __builtin_memcpy(&bits, &hv, 4);
            astore32(hn32 + (size_t)jc * 128 + bloc + (kh >> 1), bits);
        }

        gbar2(flags, bgB, rgB, (u32)(t + 2));
    } // t

    // ---- final projection: out = h_final @ W_ph + bias_p (final h in buf 0).
    // Group-confinement: block projects b = bgB*64 + rgB (own b-half).
    if (rgB < 64) {
        const int b = bgB * 64 + rgB;
        float part[CDIM];
        #pragma unroll
        for (int c2 = 0; c2 < CDIM; ++c2) part[c2] = 0.f;
        for (int k = tid; k < HDIM; k += NT) {
            const u64 hvu = aload(&g_hx[0][k][b >> 1]);
            float2 hv2; __builtin_memcpy(&hv2, &hvu, 8);
            const float hvv = (b & 1) ? hv2.y : hv2.x;
            #pragma unroll
            for (int c2 = 0; c2 < CDIM; ++c2)
                part[c2] = fmaf(hvv, Wph[(size_t)k * CDIM + c2], part[c2]);
        }
        float* red = (float*)&sW[0][0][0];   // reuse dead W LDS (48 KB needed)
        #pragma unroll
        for (int c2 = 0; c2 < CDIM; ++c2) red[tid * 12 + c2] = part[c2];
        __syncthreads();
        for (int s = NT / 2; s > 0; s >>= 1) {
            if (tid < s) {
                #pragma unroll
                for (int c2 = 0; c2 < CDIM; ++c2)
                    red[tid * 12 + c2] += red[(tid + s) * 12 + c2];
            }
            __syncthreads();
        }
        if (tid < CDIM) out[(size_t)b * CDIM + tid] = red[tid] + bp[tid];
    }
}

extern "C" void kernel_launch(void* const* d_in, const int* in_sizes, int n_in,
                              void* d_out, int out_size, void* d_ws, size_t ws_size,
                              hipStream_t stream) {
    const float* x   = (const float*)d_in[0];
    const float* Wgx = (const float*)d_in[1];
    const float* Wgh = (const float*)d_in[2];
    const float* bg  = (const float*)d_in[3];
    const float* Wix = (const float*)d_in[4];
    const float* Wih = (const float*)d_in[5];
    const float* bi  = (const float*)d_in[6];
    const float* Wfx = (const float*)d_in[7];
    const float* Wfh = (const float*)d_in[8];
    const float* bf  = (const float*)d_in[9];
    const float* Wox = (const float*)d_in[10];
    const float* Woh = (const float*)d_in[11];
    const float* bo  = (const float*)d_in[12];
    const float* Wph = (const float*)d_in[13];
    const float* bp  = (const float*)d_in[14];
    u32* flags = (u32*)d_ws;               // u32[2][128] monotonic arrival flags
    float* out = (float*)d_out;

    (void)hipMemsetAsync(d_ws, 0, 2 * 128 * sizeof(u32), stream);   // capturable node

    void* args[] = {&x, &Wgx, &Wgh, &bg, &Wix, &Wih, &bi, &Wfx, &Wfh, &bf,
                    &Wox, &Woh, &bo, &Wph, &bp, &flags, &out};
    hipError_t rc = hipLaunchCooperativeKernel((void*)lstm_fused, dim3(NWG), dim3(NT),
                                               args, 0, stream);
    if (rc != hipSuccess) {
        // Custom barrier needs no cooperative-runtime support; 256 blocks at
        // 1 block/CU are fully co-resident under a regular launch too.
        lstm_fused<<<dim3(NWG), dim3(NT), 0, stream>>>(
            x, Wgx, Wgh, bg, Wix, Wih, bi, Wfx, Wfh, bf,
            Wox, Woh, bo, Wph, bp, flags, out);
    }
}

// Round 10
// 7242.473 us; speedup vs baseline: 2.2209x; 2.2209x over previous
//
#include <hip/hip_runtime.h>
#include <cmath>

#define BATCH 128
#define TLEN  256
#define HDIM  1024
#define CDIM  10
#define NT    1024
#define NWG   256

typedef unsigned long long u64;
typedef unsigned int u32;

// h state, double buffered, k-major, u64 = 2 packed floats: g_hx[buf][j][b/2].
// ALL h accesses are relaxed agent-scope atomics (sc1) -> no cache fences;
// x/W/bias stay warm in L1/L2 across all 256 steps.
__device__ u64 g_hx[2][HDIM][BATCH / 2];

__device__ __forceinline__ float4 ld4(const float* p) { return *(const float4*)p; }

__device__ __forceinline__ u64 aload(const u64* p) {
    return __hip_atomic_load(p, __ATOMIC_RELAXED, __HIP_MEMORY_SCOPE_AGENT);
}
__device__ __forceinline__ void astore(u64* p, u64 v) {
    __hip_atomic_store(p, v, __ATOMIC_RELAXED, __HIP_MEMORY_SCOPE_AGENT);
}
__device__ __forceinline__ void astore32(u32* p, u32 v) {
    __hip_atomic_store(p, v, __ATOMIC_RELAXED, __HIP_MEMORY_SCOPE_AGENT);
}

// LDS-only barrier (R13): full lgkm drain; used OUTSIDE the phase loop.
__device__ __forceinline__ void barrier_lds() {
    asm volatile("s_waitcnt lgkmcnt(0)\n\ts_barrier" ::: "memory");
}

// Group barrier (R11/R12-proven): parallel arrivals on 128 distinct flags,
// per-wave self-release poll, monotonic targets, bounded spin.
// Keeps its explicit vmcnt(0): it is the h-publish release fence.
__device__ __forceinline__ void gbar2(u32* flags, int grp, int idx, u32 target) {
    asm volatile("s_waitcnt vmcnt(0)" ::: "memory");
    __syncthreads();
    if (threadIdx.x == 0)
        astore32(flags + grp * 128 + idx, target);
    const u64* base = (const u64*)(flags + grp * 128) + (threadIdx.x & 63);
    int guard = 0;
    for (;;) {
        const u64 v = aload(base);
        const bool ok = ((u32)v >= target) && ((u32)(v >> 32) >= target);
        if (__all(ok) || ++guard > (1 << 20)) break;
        __builtin_amdgcn_s_sleep(1);
    }
}

#define FMA4(d, s, v) do { (d).x = fmaf((s), (v).x, (d).x); (d).y = fmaf((s), (v).y, (d).y); \
                           (d).z = fmaf((s), (v).z, (d).z); (d).w = fmaf((s), (v).w, (d).w); } while (0)
#define ADD4(d, s)     do { (d).x += (s).x; (d).y += (s).y; (d).z += (s).z; (d).w += (s).w; } while (0)

// R20: FULL operand prefetch (W + h), counted waits, alternating reg sets.
// R17/R18 post-mortem: lgkmcnt is in-order, so ANY in-phase-consumed LDS read
// (w0/w1 there) forces the pre-FMA wait to drain the whole 16-wave LDS burst.
// Fix: phase p issues ONLY [ds_write p+2][prefetch W+h for p+1 -> other set].
//   waitA = lgkmcnt(5): allows this phase's 5 ops outstanding -> waits exactly
//     for phase p-1's prefetches = the CURRENT operands. ~0 stall (had a full
//     phase to land).
//   FMA burst p (register-only).
//   waitB = lgkmcnt(4): forces this phase's ds_write (oldest of the 5) done
//     before s_barrier -> cross-wave visibility; 4 prefetches fly across.
// Buffer hazards (3 bufs, chunk c in buf c%3):
//   - write p+2 in phase p; its buffer's last reader = prefetch of chunk p-1
//     issued phase p-2, forced complete by phase p-1's waitA (older than p-1's
//     5) -> before p-1's end barrier -> write is 1 barrier later. Safe.
//   - prefetch p+1 in phase p reads buf written in phase p-1; that write was
//     forced complete by p-1's waitB before p-1's barrier. Safe.
// Unroll-2 alternating sets (A/B) -> no reg moves -> no forced waits.
__global__ void __launch_bounds__(NT, 1)
lstm_fused(const float* __restrict__ x,
           const float* __restrict__ Wgx, const float* __restrict__ Wgh, const float* __restrict__ bg,
           const float* __restrict__ Wix, const float* __restrict__ Wih, const float* __restrict__ bi,
           const float* __restrict__ Wfx, const float* __restrict__ Wfh, const float* __restrict__ bf,
           const float* __restrict__ Wox, const float* __restrict__ Woh, const float* __restrict__ bo,
           const float* __restrict__ Wph, const float* __restrict__ bp,
           u32* __restrict__ flags, float* __restrict__ out)
{
    __shared__ float sW[8][HDIM][4];            // [j_local][k][gate], 128 KB
    __shared__ __align__(16) float sHraw[3 * 32 * 68];   // h TRIPLE buf, 26.1 KB; sS aliases bufs 0-1

    const int tid  = threadIdx.x;
    const int wave = tid >> 6;          // 0..15
    const int jq   = wave >> 2;         // j-pair index (0..3)
    const int kh   = wave & 3;          // k-quarter within chunk
    const int lane = tid & 63;
    const int ks   = lane & 7;
    const int bo8  = lane >> 3;
    const int rgB  = blockIdx.x >> 1;   // j in [8*rgB, 8*rgB+8)  == index in group
    const int bgB  = blockIdx.x & 1;    // b in [64*bgB, 64*bgB+64) == group id

    // ---- stage W once, gate-interleaved (1024 threads: 4 rows per pass) ----
    {
        auto stageW = [&](const float* Wsrc, int g) {
            #pragma unroll
            for (int it = 0; it < 2; ++it) {
                const int row = it * 4 + (tid >> 8);     // 0..7
                const int c4  = tid & 255;               // float4 column
                const float4 v = ld4(Wsrc + (size_t)(rgB * 8 + row) * HDIM + c4 * 4);
                sW[row][c4 * 4 + 0][g] = v.x;
                sW[row][c4 * 4 + 1][g] = v.y;
                sW[row][c4 * 4 + 2][g] = v.z;
                sW[row][c4 * 4 + 3][g] = v.w;
            }
        };
        stageW(Wgh, 0); stageW(Wih, 1); stageW(Wfh, 2); stageW(Woh, 3);
    }

    // epilogue cells: j = rgB*8 + jq*2 + (ks>>2); b = bgB*64 + bo8*8 + (ks&3)*2 + cell.
    const int jc = rgB * 8 + jq * 2 + (ks >> 2);
    const float4 wx4 = make_float4(Wgx[jc], Wix[jc], Wfx[jc], Wox[jc]);
    const float4 b4  = make_float4(bg[jc], bi[jc], bf[jc], bo[jc]);
    const int bloc = bgB * 64 + bo8 * 8 + (ks & 3) * 2;   // cell-0 batch index
    float cst = 0.f;                                       // my cell's c-state

    // zero h0 -- OWN b-half only: 8 j-rows x 32 u64
    if (tid < 256)
        astore(&g_hx[0][rgB * 8 + (tid >> 5)][bgB * 32 + (tid & 31)], 0ull);

    gbar2(flags, bgB, rgB, 1u);

    const int skc = tid >> 5;                   // staging: k within chunk (0..31)
    const int sbu = tid & 31;                   // staging: u64 col within 32
    const int hb0 = bgB * 32 + sbu;             // staging: u64 offset in g_hx row
    const int swoff = skc * 34 + sbu;           // u64 slot inside a buffer
    const int kc_ = kh * 8 + ks;                // this lane's k within any chunk

    // PH(P, G, C0,C1,CA,CB, N0,N1,NA,NB, WA, WB):
    //  [1] ds_write chunk P+2 (=G) into buf (P+2)%3 (base bwU)
    //  [2] prefetch W+h of chunk P+1 into the N set (h from base bnF)
    //  [3] reissue G = chunk P+4 (vmcnt; independent counter)
    //  [4] WA; FMA chunk P from the C set; [5] WB + s_barrier; advance bases.
#define PH(P, G, C0, C1, CA, CB, N0, N1, NA, NB, WA, WB)                        \
    {                                                                           \
        if ((P) + 2 < 32) ((u64*)sHraw)[bwU + swoff] = G;                       \
        __builtin_amdgcn_sched_barrier(0);                                      \
        if ((P) + 1 < 32) {                                                     \
            N0 = ld4(&sW[jq * 2 + 0][((P) + 1) * 32 + kc_][0]);                 \
            N1 = ld4(&sW[jq * 2 + 1][((P) + 1) * 32 + kc_][0]);                 \
            const float* pp_ = &sHraw[bnF + kc_ * 68 + bo8 * 8];                \
            NA = ld4(pp_); NB = ld4(pp_ + 4);                                   \
        }                                                                       \
        if ((P) + 4 < 32) G = aload(hrow + (size_t)((P) + 4) * 2048);           \
        __builtin_amdgcn_sched_barrier(0);                                      \
        asm volatile(WA ::: "memory");                                          \
        __builtin_amdgcn_sched_barrier(0);                                      \
        FMA4(acc[0][0], CA.x, C0); FMA4(acc[0][1], CA.y, C0);                   \
        FMA4(acc[0][2], CA.z, C0); FMA4(acc[0][3], CA.w, C0);                   \
        FMA4(acc[0][4], CB.x, C0); FMA4(acc[0][5], CB.y, C0);                   \
        FMA4(acc[0][6], CB.z, C0); FMA4(acc[0][7], CB.w, C0);                   \
        FMA4(acc[1][0], CA.x, C1); FMA4(acc[1][1], CA.y, C1);                   \
        FMA4(acc[1][2], CA.z, C1); FMA4(acc[1][3], CA.w, C1);                   \
        FMA4(acc[1][4], CB.x, C1); FMA4(acc[1][5], CB.y, C1);                   \
        FMA4(acc[1][6], CB.z, C1); FMA4(acc[1][7], CB.w, C1);                   \
        __builtin_amdgcn_sched_barrier(0);                                      \
        asm volatile(WB "\n\ts_barrier" ::: "memory");                          \
        __builtin_amdgcn_sched_barrier(0);                                      \
        bwU += 1088; if (bwU >= 3264) bwU -= 3264;                              \
        bnF += 2176; if (bnF >= 6528) bnF -= 6528;                              \
    }

    for (int t = 0; t < TLEN; ++t) {
        const u64* hc = &g_hx[t & 1][0][0];
        u32*       hn32 = (u32*)&g_hx[(t + 1) & 1][0][0];

        const u64* hrow = hc + (size_t)skc * 64 + hb0;
        // prologue: stage chunks 0 (buf0), 1 (buf1); preload A,B = chunks 2,3
        {
            const u64 g0 = aload(hrow);
            const u64 g1 = aload(hrow + 2048);
            ((u64*)sHraw)[swoff]        = g0;
            ((u64*)sHraw)[1088 + swoff] = g1;
        }
        u64 A = aload(hrow + 2 * 2048);
        u64 B = aload(hrow + 3 * 2048);

        // x for my epilogue cell (kh0 -> b, kh2 -> b+1), L1-warm
        float xv = 0.f;
        if ((kh & 1) == 0)
            xv = x[(size_t)(bloc + (kh >> 1)) * TLEN + t];

        barrier_lds();                  // staging writes drained; A,B,x in flight

        // chunk-0 prefetch into set A (4 lgkm ops; consumed by phase-0's waitA)
        float4 w0A, w1A, hAA, hBA, w0B, w1B, hAB, hBB;
        {
            w0A = ld4(&sW[jq * 2 + 0][kc_][0]);
            w1A = ld4(&sW[jq * 2 + 1][kc_][0]);
            const float* h0p_ = &sHraw[kc_ * 68 + bo8 * 8];
            hAA = ld4(h0p_); hBA = ld4(h0p_ + 4);
        }
        int bwU = 2176;                 // u64 base: phase-0 write buf = buf2
        int bnF = 2176;                 // float base: phase-0 prefetch buf = buf1

        float4 acc[2][8];   // [j_local][b]; components = 4 gates. STATIC indices only.
        #pragma unroll
        for (int jl = 0; jl < 2; ++jl)
            #pragma unroll
            for (int cb = 0; cb < 8; ++cb)
                acc[jl][cb] = make_float4(0.f, 0.f, 0.f, 0.f);

        #pragma unroll 1
        for (int cc = 0; cc < 15; ++cc) {
            const int e0 = cc * 2;      // 0..28: write+prefetch always present
            PH(e0,     A, w0A, w1A, hAA, hBA, w0B, w1B, hAB, hBB,
               "s_waitcnt lgkmcnt(5)", "s_waitcnt lgkmcnt(4)");
            PH(e0 + 1, B, w0B, w1B, hAB, hBB, w0A, w1A, hAA, hBA,
               "s_waitcnt lgkmcnt(5)", "s_waitcnt lgkmcnt(4)");
        }
        // peeled tail: P=30 (no write, prefetch 31), P=31 (nothing pending)
        PH(30, A, w0A, w1A, hAA, hBA, w0B, w1B, hAB, hBB,
           "s_waitcnt lgkmcnt(4)", "s_waitcnt lgkmcnt(4)");
        PH(31, B, w0B, w1B, hAB, hBB, w0A, w1A, hAA, hBA,
           "s_waitcnt lgkmcnt(0)", "s_waitcnt lgkmcnt(0)");
        // PH(31)'s lgkmcnt(0): no lgkm outstanding -> sS alias of bufs 0-1 safe

        // ---- intra-wave recursive-halving reduction over ks (56 shfl) ----
        float4 r1[8];
        #pragma unroll
        for (int i = 0; i < 8; ++i) {
            const float4 fs = (ks & 4) ? acc[0][i] : acc[1][i];
            float4 fr;
            fr.x = __shfl_xor(fs.x, 4); fr.y = __shfl_xor(fs.y, 4);
            fr.z = __shfl_xor(fs.z, 4); fr.w = __shfl_xor(fs.w, 4);
            const float4 fk = (ks & 4) ? acc[1][i] : acc[0][i];
            r1[i] = make_float4(fk.x + fr.x, fk.y + fr.y, fk.z + fr.z, fk.w + fr.w);
        }
        float4 r2[4];
        #pragma unroll
        for (int i = 0; i < 4; ++i) {
            const float4 fs = (ks & 2) ? r1[i] : r1[i + 4];
            float4 fr;
            fr.x = __shfl_xor(fs.x, 2); fr.y = __shfl_xor(fs.y, 2);
            fr.z = __shfl_xor(fs.z, 2); fr.w = __shfl_xor(fs.w, 2);
            const float4 fk = (ks & 2) ? r1[i + 4] : r1[i];
            r2[i] = make_float4(fk.x + fr.x, fk.y + fr.y, fk.z + fr.z, fk.w + fr.w);
        }
        float4 q0, q1;
        {
            const float4 fs0 = (ks & 1) ? r2[0] : r2[2];
            const float4 fs1 = (ks & 1) ? r2[1] : r2[3];
            float4 fr0, fr1;
            fr0.x = __shfl_xor(fs0.x, 1); fr0.y = __shfl_xor(fs0.y, 1);
            fr0.z = __shfl_xor(fs0.z, 1); fr0.w = __shfl_xor(fs0.w, 1);
            fr1.x = __shfl_xor(fs1.x, 1); fr1.y = __shfl_xor(fs1.y, 1);
            fr1.z = __shfl_xor(fs1.z, 1); fr1.w = __shfl_xor(fs1.w, 1);
            const float4 fk0 = (ks & 1) ? r2[2] : r2[0];
            const float4 fk1 = (ks & 1) ? r2[3] : r2[1];
            q0 = make_float4(fk0.x + fr0.x, fk0.y + fr0.y, fk0.z + fr0.z, fk0.w + fr0.w);
            q1 = make_float4(fk1.x + fr1.x, fk1.y + fr1.y, fk1.z + fr1.z, fk1.w + fr1.w);
        }
        // q0,q1 = partial (this kh) preacts for cells (jc, bloc) and (jc, bloc+1)

        // ---- cross-kh reduction via LDS aliased onto dead sH (bufs 0-1) ----
        float4* sS = (float4*)sHraw;    // 1024 f4 = 16 KB <= 17.4 KB (bufs 0-1)
        if (kh & 1) {                   // kh1 -> slot(jq,0), kh3 -> slot(jq,1)
            const int sl = ((jq * 2 + (kh >> 1)) * 64 + lane) * 2;
            sS[sl]     = q0;
            sS[sl + 1] = q1;
        }
        barrier_lds();
        if ((kh & 1) == 0) {            // kh0 adds kh1; kh2 adds kh3
            const int sl = ((jq * 2 + (kh >> 1)) * 64 + lane) * 2;
            ADD4(q0, sS[sl]);
            ADD4(q1, sS[sl + 1]);
        }
        // stage 2: kh0 surrenders q1, kh2 surrenders q0 (each keeps its cell)
        if (kh == 0) sS[((jq * 2 + 0) * 64 + lane) * 2 + 1] = q1;
        if (kh == 2) sS[((jq * 2 + 1) * 64 + lane) * 2 + 0] = q0;
        barrier_lds();

        if ((kh & 1) == 0) {
            float4 qq;
            if (kh == 0) {
                ADD4(q0, sS[((jq * 2 + 1) * 64 + lane) * 2 + 0]);
                qq = q0;
            } else {
                ADD4(q1, sS[((jq * 2 + 0) * 64 + lane) * 2 + 1]);
                qq = q1;
            }
            FMA4(qq, xv, wx4);
            qq.x += b4.x; qq.y += b4.y; qq.z += b4.z; qq.w += b4.w;
            const float g_ = tanhf(qq.x);
            const float i_ = 1.f / (1.f + expf(-qq.y));
            const float f_ = 1.f / (1.f + expf(-qq.z));
            const float o_ = 1.f / (1.f + expf(-qq.w));
            cst = g_ * i_ + cst * f_;
            const float hv = tanhf(cst) * o_;
            u32 bits; __builtin_memcpy(&bits, &hv, 4);
            astore32(hn32 + (size_t)jc * 128 + bloc + (kh >> 1), bits);
        }

        gbar2(flags, bgB, rgB, (u32)(t + 2));
    } // t
#undef PH

    // ---- final projection: out = h_final @ W_ph + bias_p (final h in buf 0).
    // Group-confinement: block projects b = bgB*64 + rgB (own b-half).
    if (rgB < 64) {
        const int b = bgB * 64 + rgB;
        float part[CDIM];
        #pragma unroll
        for (int c2 = 0; c2 < CDIM; ++c2) part[c2] = 0.f;
        for (int k = tid; k < HDIM; k += NT) {
            const u64 hvu = aload(&g_hx[0][k][b >> 1]);
            float2 hv2; __builtin_memcpy(&hv2, &hvu, 8);
            const float hvv = (b & 1) ? hv2.y : hv2.x;
            #pragma unroll
            for (int c2 = 0; c2 < CDIM; ++c2)
                part[c2] = fmaf(hvv, Wph[(size_t)k * CDIM + c2], part[c2]);
        }
        float* red = (float*)&sW[0][0][0];   // reuse dead W LDS (48 KB needed)
        #pragma unroll
        for (int c2 = 0; c2 < CDIM; ++c2) red[tid * 12 + c2] = part[c2];
        __syncthreads();
        for (int s = NT / 2; s > 0; s >>= 1) {
            if (tid < s) {
                #pragma unroll
                for (int c2 = 0; c2 < CDIM; ++c2)
                    red[tid * 12 + c2] += red[(tid + s) * 12 + c2];
            }
            __syncthreads();
        }
        if (tid < CDIM) out[(size_t)b * CDIM + tid] = red[tid] + bp[tid];
    }
}

extern "C" void kernel_launch(void* const* d_in, const int* in_sizes, int n_in,
                              void* d_out, int out_size, void* d_ws, size_t ws_size,
                              hipStream_t stream) {
    const float* x   = (const float*)d_in[0];
    const float* Wgx = (const float*)d_in[1];
    const float* Wgh = (const float*)d_in[2];
    const float* bg  = (const float*)d_in[3];
    const float* Wix = (const float*)d_in[4];
    const float* Wih = (const float*)d_in[5];
    const float* bi  = (const float*)d_in[6];
    const float* Wfx = (const float*)d_in[7];
    const float* Wfh = (const float*)d_in[8];
    const float* bf  = (const float*)d_in[9];
    const float* Wox = (const float*)d_in[10];
    const float* Woh = (const float*)d_in[11];
    const float* bo  = (const float*)d_in[12];
    const float* Wph = (const float*)d_in[13];
    const float* bp  = (const float*)d_in[14];
    u32* flags = (u32*)d_ws;               // u32[2][128] monotonic arrival flags
    float* out = (float*)d_out;

    (void)hipMemsetAsync(d_ws, 0, 2 * 128 * sizeof(u32), stream);   // capturable node

    void* args[] = {&x, &Wgx, &Wgh, &bg, &Wix, &Wih, &bi, &Wfx, &Wfh, &bf,
                    &Wox, &Woh, &bo, &Wph, &bp, &flags, &out};
    hipError_t rc = hipLaunchCooperativeKernel((void*)lstm_fused, dim3(NWG), dim3(NT),
                                               args, 0, stream);
    if (rc != hipSuccess) {
        // Custom barrier needs no cooperative-runtime support; 256 blocks at
        // 1 block/CU are fully co-resident under a regular launch too.
        lstm_fused<<<dim3(NWG), dim3(NT), 0, stream>>>(
            x, Wgx, Wgh, bg, Wix, Wih, bi, Wfx, Wfh, bf,
            Wox, Woh, bo, Wph, bp, flags, out);
    }
}

// Round 11
// 6380.526 us; speedup vs baseline: 2.5209x; 1.1351x over previous
//
#include <hip/hip_runtime.h>
#include <cmath>

#define BATCH 128
#define TLEN  256
#define HDIM  1024
#define CDIM  10
#define NT    1024
#define NWG   256

typedef unsigned long long u64;
typedef unsigned int u32;

// h state, double buffered, k-major, u64 = 2 packed floats: g_hx[buf][j][b/2].
// ALL h accesses are relaxed agent-scope atomics (sc1) -> no cache fences;
// x/W/bias stay warm in L1/L2 across all 256 steps.
__device__ u64 g_hx[2][HDIM][BATCH / 2];

__device__ __forceinline__ float4 ld4(const float* p) { return *(const float4*)p; }

__device__ __forceinline__ u64 aload(const u64* p) {
    return __hip_atomic_load(p, __ATOMIC_RELAXED, __HIP_MEMORY_SCOPE_AGENT);
}
__device__ __forceinline__ void astore(u64* p, u64 v) {
    __hip_atomic_store(p, v, __ATOMIC_RELAXED, __HIP_MEMORY_SCOPE_AGENT);
}
__device__ __forceinline__ void astore32(u32* p, u32 v) {
    __hip_atomic_store(p, v, __ATOMIC_RELAXED, __HIP_MEMORY_SCOPE_AGENT);
}

// R13: LDS-only barrier (intra-block barriers only protect LDS handoffs).
__device__ __forceinline__ void barrier_lds() {
    asm volatile("s_waitcnt lgkmcnt(0)\n\ts_barrier" ::: "memory");
}

// Group barrier (R11/R12-proven): parallel arrivals on 128 distinct flags,
// per-wave self-release poll, monotonic targets, bounded spin.
// Keeps its explicit vmcnt(0): it is the h-publish release fence.
__device__ __forceinline__ void gbar2(u32* flags, int grp, int idx, u32 target) {
    asm volatile("s_waitcnt vmcnt(0)" ::: "memory");
    __syncthreads();
    if (threadIdx.x == 0)
        astore32(flags + grp * 128 + idx, target);
    const u64* base = (const u64*)(flags + grp * 128) + (threadIdx.x & 63);
    int guard = 0;
    for (;;) {
        const u64 v = aload(base);
        const bool ok = ((u32)v >= target) && ((u32)(v >> 32) >= target);
        if (__all(ok) || ++guard > (1 << 20)) break;
        __builtin_amdgcn_s_sleep(1);
    }
}

#define FMA4(d, s, v) do { (d).x = fmaf((s), (v).x, (d).x); (d).y = fmaf((s), (v).y, (d).y); \
                           (d).z = fmaf((s), (v).z, (d).z); (d).w = fmaf((s), (v).w, (d).w); } while (0)
#define ADD4(d, s)     do { (d).x += (s).x; (d).y += (s).y; (d).z += (s).z; (d).w += (s).w; } while (0)

// R21: XOR-swizzled h staging (T2 applied to this layout). The old layout's
// h-read word ≡ 4*ks + 8*(bo8&3) (mod 32) -> 64 lanes on 8 spans = 8-way
// bank conflict, measured 265 cyc/phase (5.57e8/dispatch). Swizzle 32B groups
// within each k-row by group^=(k&7) on BOTH sides (same involution):
//   write: u64 col' = ((sbu>>2) ^ (skc&7))*4 + (sbu&3)   [still conflict-free]
//   read : float off = kc_*68 + (bo8 ^ ks)*8             [tiles all 32 banks
//          exactly once per 8-lane group -> conflict-free]
// Data mapping bijective; reader fetches identical values; FMA order unchanged
// -> bitwise-identical results (absmax 0.0).
// Carried from R17: distance-1 register prefetch of h operands (neutral but
// never harmful; best-measured base 6190).
__global__ void __launch_bounds__(NT, 1)
lstm_fused(const float* __restrict__ x,
           const float* __restrict__ Wgx, const float* __restrict__ Wgh, const float* __restrict__ bg,
           const float* __restrict__ Wix, const float* __restrict__ Wih, const float* __restrict__ bi,
           const float* __restrict__ Wfx, const float* __restrict__ Wfh, const float* __restrict__ bf,
           const float* __restrict__ Wox, const float* __restrict__ Woh, const float* __restrict__ bo,
           const float* __restrict__ Wph, const float* __restrict__ bp,
           u32* __restrict__ flags, float* __restrict__ out)
{
    __shared__ float sW[8][HDIM][4];            // [j_local][k][gate], 128 KB
    __shared__ __align__(16) float sHraw[2 * 32 * 68];   // h dbuf, 17 KB; aliased by sS after last phase

    const int tid  = threadIdx.x;
    const int wave = tid >> 6;          // 0..15
    const int jq   = wave >> 2;         // j-pair index (0..3)
    const int kh   = wave & 3;          // k-quarter within chunk
    const int lane = tid & 63;
    const int ks   = lane & 7;
    const int bo8  = lane >> 3;
    const int rgB  = blockIdx.x >> 1;   // j in [8*rgB, 8*rgB+8)  == index in group
    const int bgB  = blockIdx.x & 1;    // b in [64*bgB, 64*bgB+64) == group id

    // ---- stage W once, gate-interleaved (1024 threads: 4 rows per pass) ----
    {
        auto stageW = [&](const float* Wsrc, int g) {
            #pragma unroll
            for (int it = 0; it < 2; ++it) {
                const int row = it * 4 + (tid >> 8);     // 0..7
                const int c4  = tid & 255;               // float4 column
                const float4 v = ld4(Wsrc + (size_t)(rgB * 8 + row) * HDIM + c4 * 4);
                sW[row][c4 * 4 + 0][g] = v.x;
                sW[row][c4 * 4 + 1][g] = v.y;
                sW[row][c4 * 4 + 2][g] = v.z;
                sW[row][c4 * 4 + 3][g] = v.w;
            }
        };
        stageW(Wgh, 0); stageW(Wih, 1); stageW(Wfh, 2); stageW(Woh, 3);
    }

    // epilogue cells: j = rgB*8 + jq*2 + (ks>>2); b = bgB*64 + bo8*8 + (ks&3)*2 + cell.
    const int jc = rgB * 8 + jq * 2 + (ks >> 2);
    const float4 wx4 = make_float4(Wgx[jc], Wix[jc], Wfx[jc], Wox[jc]);
    const float4 b4  = make_float4(bg[jc], bi[jc], bf[jc], bo[jc]);
    const int bloc = bgB * 64 + bo8 * 8 + (ks & 3) * 2;   // cell-0 batch index
    float cst = 0.f;                                       // my cell's c-state

    // zero h0 -- OWN b-half only: 8 j-rows x 32 u64
    if (tid < 256)
        astore(&g_hx[0][rgB * 8 + (tid >> 5)][bgB * 32 + (tid & 31)], 0ull);

    gbar2(flags, bgB, rgB, 1u);

    const int skc = tid >> 5;                   // staging: k within chunk (0..31)
    const int sbu = tid & 31;                   // staging: u64 col within 32
    const int hb0 = bgB * 32 + sbu;             // staging: u64 offset in g_hx row
    const int swA = 0;                          // buf0 base (u64 units)
    const int swB = 1088;                       // buf1 base
    // R21 swizzle: u64 col' = ((sbu>>2) ^ (skc&7))*4 + (sbu&3)
    const int swoff = skc * 34 + (((sbu >> 2) ^ (skc & 7)) << 2) + (sbu & 3);
    const int kc_ = kh * 8 + ks;                // this lane's k within any chunk
    const int xg8 = (bo8 ^ ks) * 8;             // R21 swizzled 32B-group float offset

    // PH(P, G, SB, NB): [1] prefetch chunk P+1 from float-base NB; [2] ds_write
    // chunk P+2 (= G) at u64-base SB (buf P%2); [3] G = load chunk P+4;
    // [4] FMA chunk P from hAc/hBc (identical sequence to proven COMP).
#define PH(P, G, SB, NB)                                                        \
    {                                                                           \
        if ((P) + 1 < 32) {                                                     \
            const float* pp_ = &sHraw[(NB) + kc_ * 68 + xg8];                   \
            hAn = ld4(pp_); hBn = ld4(pp_ + 4);                                 \
        }                                                                       \
        if ((P) + 2 < 32) ((u64*)sHraw)[(SB) + swoff] = G;                      \
        if ((P) + 4 < 32) G = aload(hrow + (size_t)((P) + 4) * 2048);           \
        {                                                                       \
            const float4 w0 = ld4(&sW[jq * 2 + 0][(P) * 32 + kc_][0]);          \
            const float4 w1 = ld4(&sW[jq * 2 + 1][(P) * 32 + kc_][0]);          \
            FMA4(acc[0][0], hAc.x, w0); FMA4(acc[0][1], hAc.y, w0);             \
            FMA4(acc[0][2], hAc.z, w0); FMA4(acc[0][3], hAc.w, w0);             \
            FMA4(acc[0][4], hBc.x, w0); FMA4(acc[0][5], hBc.y, w0);             \
            FMA4(acc[0][6], hBc.z, w0); FMA4(acc[0][7], hBc.w, w0);             \
            FMA4(acc[1][0], hAc.x, w1); FMA4(acc[1][1], hAc.y, w1);             \
            FMA4(acc[1][2], hAc.z, w1); FMA4(acc[1][3], hAc.w, w1);             \
            FMA4(acc[1][4], hBc.x, w1); FMA4(acc[1][5], hBc.y, w1);             \
            FMA4(acc[1][6], hBc.z, w1); FMA4(acc[1][7], hBc.w, w1);             \
        }                                                                       \
        barrier_lds();                                                          \
        hAc = hAn; hBc = hBn;                                                   \
    }

    for (int t = 0; t < TLEN; ++t) {
        const u64* hc = &g_hx[t & 1][0][0];
        u32*       hn32 = (u32*)&g_hx[(t + 1) & 1][0][0];

        const u64* hrow = hc + (size_t)skc * 64 + hb0;
        // prologue: stage chunks 0,1 directly; preload A,B with chunks 2,3
        {
            const u64 g0 = aload(hrow);
            const u64 g1 = aload(hrow + 2048);
            ((u64*)sHraw)[swA + swoff] = g0;
            ((u64*)sHraw)[swB + swoff] = g1;
        }
        u64 A = aload(hrow + 2 * 2048);
        u64 B = aload(hrow + 3 * 2048);

        // x for my epilogue cell (kh0 -> b, kh2 -> b+1), L1-warm
        float xv = 0.f;
        if ((kh & 1) == 0)
            xv = x[(size_t)(bloc + (kh >> 1)) * TLEN + t];

        barrier_lds();                  // chunks 0,1 staged; A,B stay in flight

        // reg-prefetch chunk 0 (epoch protected by the next barrier: phase 0's
        // ds_write into buf0 must not overlap these buf0 reads)
        float4 hAc, hBc;
        {
            const float* h0p_ = &sHraw[kc_ * 68 + xg8];
            hAc = ld4(h0p_); hBc = ld4(h0p_ + 4);
        }
        barrier_lds();

        float4 hAn = make_float4(0.f, 0.f, 0.f, 0.f);
        float4 hBn = make_float4(0.f, 0.f, 0.f, 0.f);

        float4 acc[2][8];   // [j_local][b]; components = 4 gates. STATIC indices only.
        #pragma unroll
        for (int jl = 0; jl < 2; ++jl)
            #pragma unroll
            for (int cb = 0; cb < 8; ++cb)
                acc[jl][cb] = make_float4(0.f, 0.f, 0.f, 0.f);

        #pragma unroll 1
        for (int cc = 0; cc < 16; ++cc) {
            const int e0 = cc * 2;
            PH(e0,     A, swA, 2176);   // even phase: write buf0, prefetch from buf1
            PH(e0 + 1, B, swB, 0);      // odd  phase: write buf1, prefetch from buf0
        }
        // last phase's barrier: all sH reads done -> sS alias safe

        // ---- intra-wave recursive-halving reduction over ks (56 shfl) ----
        float4 r1[8];
        #pragma unroll
        for (int i = 0; i < 8; ++i) {
            const float4 fs = (ks & 4) ? acc[0][i] : acc[1][i];
            float4 fr;
            fr.x = __shfl_xor(fs.x, 4); fr.y = __shfl_xor(fs.y, 4);
            fr.z = __shfl_xor(fs.z, 4); fr.w = __shfl_xor(fs.w, 4);
            const float4 fk = (ks & 4) ? acc[1][i] : acc[0][i];
            r1[i] = make_float4(fk.x + fr.x, fk.y + fr.y, fk.z + fr.z, fk.w + fr.w);
        }
        float4 r2[4];
        #pragma unroll
        for (int i = 0; i < 4; ++i) {
            const float4 fs = (ks & 2) ? r1[i] : r1[i + 4];
            float4 fr;
            fr.x = __shfl_xor(fs.x, 2); fr.y = __shfl_xor(fs.y, 2);
            fr.z = __shfl_xor(fs.z, 2); fr.w = __shfl_xor(fs.w, 2);
            const float4 fk = (ks & 2) ? r1[i + 4] : r1[i];
            r2[i] = make_float4(fk.x + fr.x, fk.y + fr.y, fk.z + fr.z, fk.w + fr.w);
        }
        float4 q0, q1;
        {
            const float4 fs0 = (ks & 1) ? r2[0] : r2[2];
            const float4 fs1 = (ks & 1) ? r2[1] : r2[3];
            float4 fr0, fr1;
            fr0.x = __shfl_xor(fs0.x, 1); fr0.y = __shfl_xor(fs0.y, 1);
            fr0.z = __shfl_xor(fs0.z, 1); fr0.w = __shfl_xor(fs0.w, 1);
            fr1.x = __shfl_xor(fs1.x, 1); fr1.y = __shfl_xor(fs1.y, 1);
            fr1.z = __shfl_xor(fs1.z, 1); fr1.w = __shfl_xor(fs1.w, 1);
            const float4 fk0 = (ks & 1) ? r2[2] : r2[0];
            const float4 fk1 = (ks & 1) ? r2[3] : r2[1];
            q0 = make_float4(fk0.x + fr0.x, fk0.y + fr0.y, fk0.z + fr0.z, fk0.w + fr0.w);
            q1 = make_float4(fk1.x + fr1.x, fk1.y + fr1.y, fk1.z + fr1.z, fk1.w + fr1.w);
        }
        // q0,q1 = partial (this kh) preacts for cells (jc, bloc) and (jc, bloc+1)

        // ---- cross-kh reduction via LDS aliased onto dead sH ----
        float4* sS = (float4*)sHraw;    // 1024 f4 = 16 KB <= 17.4 KB
        if (kh & 1) {                   // kh1 -> slot(jq,0), kh3 -> slot(jq,1)
            const int sl = ((jq * 2 + (kh >> 1)) * 64 + lane) * 2;
            sS[sl]     = q0;
            sS[sl + 1] = q1;
        }
        barrier_lds();
        if ((kh & 1) == 0) {            // kh0 adds kh1; kh2 adds kh3
            const int sl = ((jq * 2 + (kh >> 1)) * 64 + lane) * 2;
            ADD4(q0, sS[sl]);
            ADD4(q1, sS[sl + 1]);
        }
        // stage 2: kh0 surrenders q1, kh2 surrenders q0 (each keeps its cell)
        if (kh == 0) sS[((jq * 2 + 0) * 64 + lane) * 2 + 1] = q1;
        if (kh == 2) sS[((jq * 2 + 1) * 64 + lane) * 2 + 0] = q0;
        barrier_lds();

        if ((kh & 1) == 0) {
            float4 qq;
            if (kh == 0) {
                ADD4(q0, sS[((jq * 2 + 1) * 64 + lane) * 2 + 0]);
                qq = q0;
            } else {
                ADD4(q1, sS[((jq * 2 + 0) * 64 + lane) * 2 + 1]);
                qq = q1;
            }
            FMA4(qq, xv, wx4);
            qq.x += b4.x; qq.y += b4.y; qq.z += b4.z; qq.w += b4.w;
            const float g_ = tanhf(qq.x);
            const float i_ = 1.f / (1.f + expf(-qq.y));
            const float f_ = 1.f / (1.f + expf(-qq.z));
            const float o_ = 1.f / (1.f + expf(-qq.w));
            cst = g_ * i_ + cst * f_;
            const float hv = tanhf(cst) * o_;
            u32 bits; __builtin_memcpy(&bits, &hv, 4);
            astore32(hn32 + (size_t)jc * 128 + bloc + (kh >> 1), bits);
        }

        gbar2(flags, bgB, rgB, (u32)(t + 2));
    } // t
#undef PH

    // ---- final projection: out = h_final @ W_ph + bias_p (final h in buf 0).
    // Group-confinement: block projects b = bgB*64 + rgB (own b-half).
    if (rgB < 64) {
        const int b = bgB * 64 + rgB;
        float part[CDIM];
        #pragma unroll
        for (int c2 = 0; c2 < CDIM; ++c2) part[c2] = 0.f;
        for (int k = tid; k < HDIM; k += NT) {
            const u64 hvu = aload(&g_hx[0][k][b >> 1]);
            float2 hv2; __builtin_memcpy(&hv2, &hvu, 8);
            const float hvv = (b & 1) ? hv2.y : hv2.x;
            #pragma unroll
            for (int c2 = 0; c2 < CDIM; ++c2)
                part[c2] = fmaf(hvv, Wph[(size_t)k * CDIM + c2], part[c2]);
        }
        float* red = (float*)&sW[0][0][0];   // reuse dead W LDS (48 KB needed)
        #pragma unroll
        for (int c2 = 0; c2 < CDIM; ++c2) red[tid * 12 + c2] = part[c2];
        __syncthreads();
        for (int s = NT / 2; s > 0; s >>= 1) {
            if (tid < s) {
                #pragma unroll
                for (int c2 = 0; c2 < CDIM; ++c2)
                    red[tid * 12 + c2] += red[(tid + s) * 12 + c2];
            }
            __syncthreads();
        }
        if (tid < CDIM) out[(size_t)b * CDIM + tid] = red[tid] + bp[tid];
    }
}

extern "C" void kernel_launch(void* const* d_in, const int* in_sizes, int n_in,
                              void* d_out, int out_size, void* d_ws, size_t ws_size,
                              hipStream_t stream) {
    const float* x   = (const float*)d_in[0];
    const float* Wgx = (const float*)d_in[1];
    const float* Wgh = (const float*)d_in[2];
    const float* bg  = (const float*)d_in[3];
    const float* Wix = (const float*)d_in[4];
    const float* Wih = (const float*)d_in[5];
    const float* bi  = (const float*)d_in[6];
    const float* Wfx = (const float*)d_in[7];
    const float* Wfh = (const float*)d_in[8];
    const float* bf  = (const float*)d_in[9];
    const float* Wox = (const float*)d_in[10];
    const float* Woh = (const float*)d_in[11];
    const float* bo  = (const float*)d_in[12];
    const float* Wph = (const float*)d_in[13];
    const float* bp  = (const float*)d_in[14];
    u32* flags = (u32*)d_ws;               // u32[2][128] monotonic arrival flags
    float* out = (float*)d_out;

    (void)hipMemsetAsync(d_ws, 0, 2 * 128 * sizeof(u32), stream);   // capturable node

    void* args[] = {&x, &Wgx, &Wgh, &bg, &Wix, &Wih, &bi, &Wfx, &Wfh, &bf,
                    &Wox, &Woh, &bo, &Wph, &bp, &flags, &out};
    hipError_t rc = hipLaunchCooperativeKernel((void*)lstm_fused, dim3(NWG), dim3(NT),
                                               args, 0, stream);
    if (rc != hipSuccess) {
        // Custom barrier needs no cooperative-runtime support; 256 blocks at
        // 1 block/CU are fully co-resident under a regular launch too.
        lstm_fused<<<dim3(NWG), dim3(NT), 0, stream>>>(
            x, Wgx, Wgh, bg, Wix, Wih, bi, Wfx, Wfh, bf,
            Wox, Woh, bo, Wph, bp, flags, out);
    }
}